// Round 5
// baseline (34.160 us; speedup 1.0000x reference)
//
#include <hip/hip_runtime.h>
#include <math.h>

#define VOCAB 100000
#define DIM 128
#define BATCH 16384
#define CTX 10
#define NEG 10
#define NSCORE (NEG + 1)
#define NROWS (CTX + NSCORE)

// Fast log_sigmoid(x) = min(x,0) - log(1 + exp(-|x|)) using HW v_exp/v_log.
__device__ __forceinline__ float log_sigmoid_f(float x) {
    const float e = __expf(-fabsf(x));
    return fminf(x, 0.0f) - __logf(1.0f + e);
}

// One wave handles TWO batch elements: lanes 0-31 -> b0, lanes 32-63 -> b1.
// Each 32-lane half owns a full D=128 row as one float4 per lane.
// All 21 row-gathers are batched into registers -> ~21 loads in flight.
__global__ __launch_bounds__(256) void cbow_main(
    const float* __restrict__ W_embed, const float* __restrict__ W_out,
    const int* __restrict__ ctx_ids, const int* __restrict__ tgt_ids,
    const int* __restrict__ neg_ids, float* __restrict__ partial)
{
    const int wave = threadIdx.x >> 6;
    const int lane = threadIdx.x & 63;
    const int half = lane >> 5;          // which batch element in this wave
    const int l32  = lane & 31;          // lane within the 32-lane row
    const int b = blockIdx.x * 8 + wave * 2 + half;

    const float4* __restrict__ We = (const float4*)W_embed;
    const float4* __restrict__ Wo = (const float4*)W_out;

    // --- phase 0: all indices first (small, L2-resident) ---
    int rows[NROWS];
    #pragma unroll
    for (int j = 0; j < CTX; ++j) rows[j] = ctx_ids[b * CTX + j];
    rows[CTX] = tgt_ids[b];
    #pragma unroll
    for (int n = 0; n < NEG; ++n) rows[CTX + 1 + n] = neg_ids[b * NEG + n];

    // --- phase 1: issue ALL 21 row gathers into registers ---
    float4 cv[CTX];
    #pragma unroll
    for (int j = 0; j < CTX; ++j)
        cv[j] = We[(unsigned)(rows[j] * 32 + l32)];
    float4 ov[NSCORE];
    #pragma unroll
    for (int n = 0; n < NSCORE; ++n)
        ov[n] = Wo[(unsigned)(rows[CTX + n] * 32 + l32)];

    // --- phase 2: context mean ---
    float mx = 0.f, my = 0.f, mz = 0.f, mw = 0.f;
    #pragma unroll
    for (int j = 0; j < CTX; ++j) {
        mx += cv[j].x; my += cv[j].y; mz += cv[j].z; mw += cv[j].w;
    }
    mx *= 0.1f; my *= 0.1f; mz *= 0.1f; mw *= 0.1f;

    // --- phase 3: 11 per-lane partial dots ---
    float p[NSCORE];
    #pragma unroll
    for (int n = 0; n < NSCORE; ++n)
        p[n] = mx * ov[n].x + my * ov[n].y + mz * ov[n].z + mw * ov[n].w;

    // --- phase 4: 11 interleaved 5-level butterflies (within 32-lane half) ---
    #pragma unroll
    for (int off = 16; off >= 1; off >>= 1) {
        #pragma unroll
        for (int n = 0; n < NSCORE; ++n)
            p[n] += __shfl_xor(p[n], off, 64);
    }

    float loss = log_sigmoid_f(p[0]);
    #pragma unroll
    for (int n = 1; n < NSCORE; ++n)
        loss += log_sigmoid_f(-p[n]);

    if (l32 == 0) partial[b] = loss;     // independent retire, no block sync
}

// Deterministic fixed-order reduction of 16384 per-element losses.
__global__ __launch_bounds__(1024) void cbow_reduce(
    const float* __restrict__ partial, float* __restrict__ out)
{
    __shared__ float s[1024];
    float v = 0.0f;
    #pragma unroll
    for (int k = 0; k < 16; ++k)
        v += partial[threadIdx.x + 1024 * k];
    s[threadIdx.x] = v;
    __syncthreads();
    for (int stride = 512; stride > 0; stride >>= 1) {
        if (threadIdx.x < stride) s[threadIdx.x] += s[threadIdx.x + stride];
        __syncthreads();
    }
    if (threadIdx.x == 0) out[0] = -s[0] / (float)BATCH;
}

extern "C" void kernel_launch(void* const* d_in, const int* in_sizes, int n_in,
                              void* d_out, int out_size, void* d_ws, size_t ws_size,
                              hipStream_t stream) {
    const float* W_embed = (const float*)d_in[0];
    const float* W_out   = (const float*)d_in[1];
    const int* ctx_ids   = (const int*)d_in[2];
    const int* tgt_ids   = (const int*)d_in[3];
    const int* neg_ids   = (const int*)d_in[4];
    float* out = (float*)d_out;
    float* partial = (float*)d_ws;   // 16384 floats, fully rewritten each call

    cbow_main<<<BATCH / 8, 256, 0, stream>>>(W_embed, W_out, ctx_ids, tgt_ids,
                                             neg_ids, partial);
    cbow_reduce<<<1, 1024, 0, stream>>>(partial, out);
}